// Round 9
// baseline (1152.418 us; speedup 1.0000x reference)
//
#include <hip/hip_runtime.h>

// LSTM: B=2048, T=4096, I=5, H=10, fp32. TWO batch chains per wave.
// Grid 1024 x 64: wave handles chains b0=2*blk, b1=2*blk+1. Lane = 4*j+k as
// before (j=unit, k=gate i/f/g/o); each lane carries BOTH chains' state
// (hA,hB,csA,csB). Shares per-wave overhead (loop, LDS x-reads, stores,
// staging) across 2 chains; readlanes/FMAs/trans duplicated per chain but
// the two chains' dependent chains interleave -> ILP hides latency at
// 1 wave/SIMD. Round-8 micro-edits (swpipe x, grouped readlanes) reverted
// (measured neutral-to-negative).
//  - W/bias pre-scaled by -log2e (-2log2e for g rows); cell carried as
//    cs = -2*log2e*c so both exp2's consume inputs directly.
//  - x staged into paired LDS: step t holds (xA[i],xB[i]) pairs, 48B stride;
//    per-step reads = b128 + b128 + b64, uniform -> broadcast.
//  - stores batched 4 steps per chain (capture cndmask, 160B segments).

#define BB 2048
#define TT 4096
#define II 5
#define HH 10
#define CH 256                 // timesteps per LDS chunk
#define CHF (CH * II)          // 1280 floats of raw x per chunk per chain
#define PSTRIDE 48             // bytes per step in LDS: 5 pairs + pad, 16B-aligned
#define BUFB (CH * PSTRIDE)    // 12288 bytes per buffer
#define NCHUNK (TT / CH)       // 16

__device__ __forceinline__ float readlane_f(float v, int l) {
    union { float f; int i; } u;
    u.f = v;
    u.i = __builtin_amdgcn_readlane(u.i, l);
    return u.f;
}

// Broadcast quad element E to all 4 lanes of each quad (DPP quad_perm).
template<int E>
__device__ __forceinline__ float quad_bcast(float v) {
    union { float f; int i; } u;
    u.f = v;
    u.i = __builtin_amdgcn_update_dpp(u.i, u.i, E * 0x55, 0xF, 0xF, false);
    return u.f;
}

__global__ __launch_bounds__(64, 1) void lstm_wave_kernel(
    const float* __restrict__ x,
    const float* __restrict__ h0,
    const float* __restrict__ c0,
    const float* __restrict__ W_ih,
    const float* __restrict__ W_hh,
    const float* __restrict__ b_ih,
    const float* __restrict__ b_hh,
    float* __restrict__ out)
{
    __shared__ __align__(16) char xs[2 * BUFB];   // 24 KiB/block; 4 blocks/CU

    const int blk = blockIdx.x;
    const int b0 = 2 * blk;
    const int b1 = b0 + 1;
    const int lane = threadIdx.x;
    const int j = lane >> 2;       // hidden unit
    const int k = lane & 3;        // gate: 0=i 1=f 2=g 3=o
    const bool active = (lane < 4 * HH);

    const float LOG2E = 1.4426950408889634f;
    const float KC = -2.f * LOG2E;                 // cell carry scale
    const float scale = (k == 2) ? KC : -LOG2E;    // preact scale folded into W

    // Per-lane gate-row weights, pre-scaled (same row serves both chains)
    float wih[II];
    float whh[HH];
    float bias = 0.f;
    if (active) {
        const int row = k * HH + j;                // gate blocks of 10 rows: i,f,g,o
#pragma unroll
        for (int q = 0; q < II; q++) wih[q] = W_ih[row * II + q] * scale;
#pragma unroll
        for (int q = 0; q < HH; q++) whh[q] = W_hh[row * HH + q] * scale;
        bias = (b_ih[row] + b_hh[row]) * scale;
    } else {
#pragma unroll
        for (int q = 0; q < II; q++) wih[q] = 0.f;
#pragma unroll
        for (int q = 0; q < HH; q++) whh[q] = 0.f;
    }

    // act = fma(s, am, ac) with s = rcp(1+exp2(acc)):
    //   sigmoid lanes: act = s.   g lane: act = KC*tanh = s*(2KC) + (-KC)
    const float am = (k == 2) ? (2.f * KC) : 1.f;
    const float ac = (k == 2) ? (-KC) : 0.f;

    float hA = 0.f, csA = 0.f, hB = 0.f, csB = 0.f;
    if (active) {
        hA  = h0[b0 * HH + j];
        csA = c0[b0 * HH + j] * KC;
        hB  = h0[b1 * HH + j];
        csB = c0[b1 * HH + j] * KC;
    }

    const float* xrowA = x + (size_t)b0 * TT * II;
    const float* xrowB = x + (size_t)b1 * TT * II;

    // Per-lane batched-store pointers: lane (j,k) writes out[b][tb+k][j].
    float* outpA = out + (size_t)b0 * TT * HH + k * HH + j;
    float* outpB = out + (size_t)b1 * TT * HH + k * HH + j;

    // Padded-LDS scatter byte-addresses for staging: raw float pos
    // p = (q*64+lane)*4 + c  ->  byte (p/5)*48 + (p%5)*8 (+4 for chain B).
    int wa[II][4];
#pragma unroll
    for (int q = 0; q < II; q++) {
#pragma unroll
        for (int c4 = 0; c4 < 4; c4++) {
            const int p = (q * 64 + lane) * 4 + c4;
            wa[q][c4] = (p / II) * PSTRIDE + (p % II) * 8;
        }
    }

    // ---- stage chunk 0 (paired scatter) ----
    float4 pfA[II], pfB[II];
    {
        const float4* xvA = (const float4*)xrowA;
        const float4* xvB = (const float4*)xrowB;
#pragma unroll
        for (int q = 0; q < II; q++) {
            pfA[q] = xvA[q * 64 + lane];
            pfB[q] = xvB[q * 64 + lane];
        }
        char* dst = xs;
#pragma unroll
        for (int q = 0; q < II; q++) {
            *(float*)(dst + wa[q][0])     = pfA[q].x;
            *(float*)(dst + wa[q][1])     = pfA[q].y;
            *(float*)(dst + wa[q][2])     = pfA[q].z;
            *(float*)(dst + wa[q][3])     = pfA[q].w;
            *(float*)(dst + wa[q][0] + 4) = pfB[q].x;
            *(float*)(dst + wa[q][1] + 4) = pfB[q].y;
            *(float*)(dst + wa[q][2] + 4) = pfB[q].z;
            *(float*)(dst + wa[q][3] + 4) = pfB[q].w;
        }
    }

    float keepA = 0.f, keepB = 0.f;   // batched-store capture registers

    for (int c = 0; c < NCHUNK; ++c) {
        const char* xc = xs + (c & 1) * BUFB;

        // issue next chunk's global loads now; consume ~256 steps later
        if (c + 1 < NCHUNK) {
            const float4* xvA = (const float4*)(xrowA + (size_t)(c + 1) * CHF);
            const float4* xvB = (const float4*)(xrowB + (size_t)(c + 1) * CHF);
#pragma unroll
            for (int q = 0; q < II; q++) {
                pfA[q] = xvA[q * 64 + lane];
                pfB[q] = xvB[q * 64 + lane];
            }
        }

#pragma unroll 8
        for (int u = 0; u < CH; ++u) {
            // x_t pairs from LDS (uniform address -> broadcast):
            // r0 = (xA0,xB0,xA1,xB1), r1 = (xA2,xB2,xA3,xB3), r2 = (xA4,xB4)
            const char* xp = xc + u * PSTRIDE;
            const float4 r0 = *(const float4*)(xp);
            const float4 r1 = *(const float4*)(xp + 16);
            const float2 r2 = *(const float2*)(xp + 32);

            // x-dot, both chains (off the recurrence chain)
            float aA0 = fmaf(r0.x, wih[0], bias);
            float aB0 = fmaf(r0.y, wih[0], bias);
            float aA1 = r0.z * wih[1];
            float aB1 = r0.w * wih[1];
            float aA2 = r1.x * wih[2];
            float aB2 = r1.y * wih[2];
            float aA3 = r1.z * wih[3];
            float aB3 = r1.w * wih[3];
            aA0 = fmaf(r2.x, wih[4], aA0);
            aB0 = fmaf(r2.y, wih[4], aB0);

            // h-dot, chain A
            aA0 = fmaf(readlane_f(hA, 0),  whh[0], aA0);
            aA1 = fmaf(readlane_f(hA, 4),  whh[1], aA1);
            aA2 = fmaf(readlane_f(hA, 8),  whh[2], aA2);
            aA3 = fmaf(readlane_f(hA, 12), whh[3], aA3);
            aA0 = fmaf(readlane_f(hA, 16), whh[4], aA0);
            aA1 = fmaf(readlane_f(hA, 20), whh[5], aA1);
            aA2 = fmaf(readlane_f(hA, 24), whh[6], aA2);
            aA3 = fmaf(readlane_f(hA, 28), whh[7], aA3);
            aA0 = fmaf(readlane_f(hA, 32), whh[8], aA0);
            aA1 = fmaf(readlane_f(hA, 36), whh[9], aA1);
            const float accA = (aA0 + aA1) + (aA2 + aA3);

            // h-dot, chain B
            aB0 = fmaf(readlane_f(hB, 0),  whh[0], aB0);
            aB1 = fmaf(readlane_f(hB, 4),  whh[1], aB1);
            aB2 = fmaf(readlane_f(hB, 8),  whh[2], aB2);
            aB3 = fmaf(readlane_f(hB, 12), whh[3], aB3);
            aB0 = fmaf(readlane_f(hB, 16), whh[4], aB0);
            aB1 = fmaf(readlane_f(hB, 20), whh[5], aB1);
            aB2 = fmaf(readlane_f(hB, 24), whh[6], aB2);
            aB3 = fmaf(readlane_f(hB, 28), whh[7], aB3);
            aB0 = fmaf(readlane_f(hB, 32), whh[8], aB0);
            aB1 = fmaf(readlane_f(hB, 36), whh[9], aB1);
            const float accB = (aB0 + aB1) + (aB2 + aB3);

            // branchless sigmoid / KC*tanh, both chains
            const float eA = __builtin_amdgcn_exp2f(accA);
            const float eB = __builtin_amdgcn_exp2f(accB);
            const float sA = __builtin_amdgcn_rcpf(1.f + eA);
            const float sB = __builtin_amdgcn_rcpf(1.f + eB);
            const float actA = fmaf(sA, am, ac);
            const float actB = fmaf(sB, am, ac);

            // quad gather: pure-VALU DPP broadcasts
            const float ivA = quad_bcast<0>(actA);
            const float fvA = quad_bcast<1>(actA);
            const float gsA = quad_bcast<2>(actA);   // already KC*g
            const float ovA = quad_bcast<3>(actA);
            const float ivB = quad_bcast<0>(actB);
            const float fvB = quad_bcast<1>(actB);
            const float gsB = quad_bcast<2>(actB);
            const float ovB = quad_bcast<3>(actB);

            // cs = KC*c:  cs' = f*cs + i*(KC*g);  tanh(c) = 2*rcp(1+exp2(cs))-1
            csA = fmaf(fvA, csA, ivA * gsA);
            csB = fmaf(fvB, csB, ivB * gsB);
            const float e2A = __builtin_amdgcn_exp2f(csA);
            const float e2B = __builtin_amdgcn_exp2f(csB);
            const float thA = fmaf(__builtin_amdgcn_rcpf(1.f + e2A), 2.f, -1.f);
            const float thB = fmaf(__builtin_amdgcn_rcpf(1.f + e2B), 2.f, -1.f);
            hA = ovA * thA;
            hB = ovB * thB;

            // batched store: lane (j,k) captures step ==k (mod 4);
            // 40 lanes store a contiguous 160B segment per chain every 4th step.
            keepA = ((u & 3) == k) ? hA : keepA;
            keepB = ((u & 3) == k) ? hB : keepB;
            if ((u & 3) == 3) {
                const int off = ((u & 7) == 3) ? 0 : 40;   // imm 0 / 160B
                if (active) {
                    outpA[off] = keepA;
                    outpB[off] = keepB;
                }
            }
            if ((u & 7) == 7) {
                outpA += 80;           // +320B per unroll-8
                outpB += 80;
            }
        }

        // park the prefetched chunk into the other LDS buffer (paired scatter)
        if (c + 1 < NCHUNK) {
            char* dst = xs + ((c + 1) & 1) * BUFB;
#pragma unroll
            for (int q = 0; q < II; q++) {
                *(float*)(dst + wa[q][0])     = pfA[q].x;
                *(float*)(dst + wa[q][1])     = pfA[q].y;
                *(float*)(dst + wa[q][2])     = pfA[q].z;
                *(float*)(dst + wa[q][3])     = pfA[q].w;
                *(float*)(dst + wa[q][0] + 4) = pfB[q].x;
                *(float*)(dst + wa[q][1] + 4) = pfB[q].y;
                *(float*)(dst + wa[q][2] + 4) = pfB[q].z;
                *(float*)(dst + wa[q][3] + 4) = pfB[q].w;
            }
        }
    }
}

extern "C" void kernel_launch(void* const* d_in, const int* in_sizes, int n_in,
                              void* d_out, int out_size, void* d_ws, size_t ws_size,
                              hipStream_t stream) {
    const float* x    = (const float*)d_in[0];
    const float* h0   = (const float*)d_in[1];
    const float* c0   = (const float*)d_in[2];
    const float* W_ih = (const float*)d_in[3];
    const float* W_hh = (const float*)d_in[4];
    const float* b_ih = (const float*)d_in[5];
    const float* b_hh = (const float*)d_in[6];
    float* out = (float*)d_out;

    lstm_wave_kernel<<<dim3(BB / 2), dim3(64), 0, stream>>>(
        x, h0, c0, W_ih, W_hh, b_ih, b_hh, out);
}

// Round 12
// 1042.168 us; speedup vs baseline: 1.1058x; 1.1058x over previous
//
#include <hip/hip_runtime.h>

// LSTM: B=2048, T=4096, I=5, H=10, fp32. One wave per batch chain (REVERT to
// the verified 785us structure; round-9 2-chain fusion regressed: trans ops /
// readlanes / FMAs scale with chains not waves, and 1 wave/SIMD exposed the
// dependent-chain latency -- VALUBusy 85->73.5%).
// QUAD LAYOUT: lane = 4*j + k  (j = hidden unit 0..9, k = gate 0..3 = i,f,g,o).
//  - gate gather is DPP quad_perm broadcast (VALU), no LDS pipe on the chain.
//  - W_ih/W_hh/bias pre-scaled by -log2e (-2log2e for g rows); cell carried as
//    cs = -2*log2e*c, so both exp2's consume their inputs directly.
//  - x staged into PADDED LDS (8 floats/step): per-step reads 1 ds_read_b128
//    + 1 ds_read_b32 (uniform -> broadcast); scatter addrs precomputed.
//  - stores batched 4 steps (capture cndmask, coalesced 160B segments).
// This round: PACKED FP32 (v_pk_mul/fma/add_f32, CDNA dual-f32 VOP3P).
//  - x-dot: 2 pk_mul + 1 scalar fma (was 5 scalar ops)
//  - h-dot: 5 pk_fma with readlane'd h-pairs as the single allowed 64-bit
//    SGPR operand (pair-assembly s_movs ride the scalar pipe, free)
//  - reduce: 1 pk_add + 1 add + 1 add (was 3 adds)
//  => 28 -> 21 VALU slots per wave-step in the issue-bound loop.

#define BB 2048
#define TT 4096
#define II 5
#define HH 10
#define CH 256                // timesteps per LDS chunk
#define CHF (CH * II)         // 1280 floats of raw x per chunk
#define PSTRIDE 32            // padded bytes per step in LDS (8 floats)
#define BUFB (CH * PSTRIDE)   // 8192 bytes per buffer
#define NCHUNK (TT / CH)      // 16

__device__ __forceinline__ float readlane_f(float v, int l) {
    union { float f; int i; } u;
    u.f = v;
    u.i = __builtin_amdgcn_readlane(u.i, l);
    return u.f;
}

// Broadcast quad element E to all 4 lanes of each quad (DPP quad_perm).
template<int E>
__device__ __forceinline__ float quad_bcast(float v) {
    union { float f; int i; } u;
    u.f = v;
    u.i = __builtin_amdgcn_update_dpp(u.i, u.i, E * 0x55, 0xF, 0xF, false);
    return u.f;
}

// Packed fp32 ops (CDNA VOP3P). d = a*b (+ d). h-pair variant takes the pair
// in SGPRs (uniform readlane results) -- the one scalar operand allowed.
__device__ __forceinline__ void pk_mul(float2& d, const float2 a, const float2 b) {
    asm("v_pk_mul_f32 %0, %1, %2" : "=v"(d) : "v"(a), "v"(b));
}
__device__ __forceinline__ void pk_fma_s(float2& d, const float2 hs, const float2 w) {
    asm("v_pk_fma_f32 %0, %1, %2, %0" : "+v"(d) : "s"(hs), "v"(w));
}
__device__ __forceinline__ void pk_add(float2& d, const float2 a, const float2 b) {
    asm("v_pk_add_f32 %0, %1, %2" : "=v"(d) : "v"(a), "v"(b));
}

__global__ __launch_bounds__(64) void lstm_wave_kernel(
    const float* __restrict__ x,
    const float* __restrict__ h0,
    const float* __restrict__ c0,
    const float* __restrict__ W_ih,
    const float* __restrict__ W_hh,
    const float* __restrict__ b_ih,
    const float* __restrict__ b_hh,
    float* __restrict__ out)
{
    __shared__ __align__(16) char xs[2][BUFB];   // 16 KiB/block; 8 blocks/CU

    const int b = blockIdx.x;
    const int lane = threadIdx.x;
    const int j = lane >> 2;       // hidden unit
    const int k = lane & 3;        // gate: 0=i 1=f 2=g 3=o
    const bool active = (lane < 4 * HH);

    const float LOG2E = 1.4426950408889634f;
    const float KC = -2.f * LOG2E;                 // cell carry scale
    const float scale = (k == 2) ? KC : -LOG2E;    // preact scale folded into W

    // Per-lane gate-row weights, pre-scaled, stored as float2 pairs for pk ops
    float2 wi01 = {0.f, 0.f}, wi23 = {0.f, 0.f};
    float  wi4 = 0.f;
    float2 w01 = {0.f, 0.f}, w23 = {0.f, 0.f}, w45 = {0.f, 0.f},
           w67 = {0.f, 0.f}, w89 = {0.f, 0.f};
    float bias = 0.f;
    if (active) {
        const int row = k * HH + j;                // gate blocks of 10 rows: i,f,g,o
        wi01.x = W_ih[row * II + 0] * scale;
        wi01.y = W_ih[row * II + 1] * scale;
        wi23.x = W_ih[row * II + 2] * scale;
        wi23.y = W_ih[row * II + 3] * scale;
        wi4    = W_ih[row * II + 4] * scale;
        w01.x = W_hh[row * HH + 0] * scale;
        w01.y = W_hh[row * HH + 1] * scale;
        w23.x = W_hh[row * HH + 2] * scale;
        w23.y = W_hh[row * HH + 3] * scale;
        w45.x = W_hh[row * HH + 4] * scale;
        w45.y = W_hh[row * HH + 5] * scale;
        w67.x = W_hh[row * HH + 6] * scale;
        w67.y = W_hh[row * HH + 7] * scale;
        w89.x = W_hh[row * HH + 8] * scale;
        w89.y = W_hh[row * HH + 9] * scale;
        bias = (b_ih[row] + b_hh[row]) * scale;
    }

    // act = fma(s, am, ac) with s = rcp(1+exp2(acc)):
    //   sigmoid lanes: act = s.   g lane: act = KC*tanh = s*(2KC) + (-KC)
    const float am = (k == 2) ? (2.f * KC) : 1.f;
    const float ac = (k == 2) ? (-KC) : 0.f;

    float hval = 0.f, cs = 0.f;
    if (active) {
        hval = h0[b * HH + j];
        cs   = c0[b * HH + j] * KC;    // carry is KC*c
    }

    const float* xrow = x + (size_t)b * TT * II;

    // Per-lane batched-store pointer: lane (j,k) writes out[b][tb+k][j].
    float* outp = out + (size_t)b * TT * HH + k * HH + j;

    // Precompute the 20 padded-LDS scatter byte-addresses for staging:
    // loaded float4 xv[q*64+lane] component c sits at raw float pos
    // p = (q*64+lane)*4 + c  ->  padded byte (p/5)*32 + (p%5)*4.
    int wa[II][4];
#pragma unroll
    for (int q = 0; q < II; q++) {
#pragma unroll
        for (int c4 = 0; c4 < 4; c4++) {
            const int p = (q * 64 + lane) * 4 + c4;
            wa[q][c4] = (p / II) * PSTRIDE + (p % II) * 4;
        }
    }

    // ---- stage chunk 0 (padded scatter) ----
    float4 pf[II];
    {
        const float4* xv = (const float4*)xrow;
#pragma unroll
        for (int q = 0; q < II; q++) pf[q] = xv[q * 64 + lane];
        char* dst = xs[0];
#pragma unroll
        for (int q = 0; q < II; q++) {
            *(float*)(dst + wa[q][0]) = pf[q].x;
            *(float*)(dst + wa[q][1]) = pf[q].y;
            *(float*)(dst + wa[q][2]) = pf[q].z;
            *(float*)(dst + wa[q][3]) = pf[q].w;
        }
    }

    float keep = 0.f;   // batched-store capture register

    for (int c = 0; c < NCHUNK; ++c) {
        const char* xc = xs[c & 1];

        // issue next chunk's global loads now; consume ~256 steps later
        if (c + 1 < NCHUNK) {
            const float4* xv = (const float4*)(xrow + (size_t)(c + 1) * CHF);
#pragma unroll
            for (int q = 0; q < II; q++) pf[q] = xv[q * 64 + lane];
        }

#pragma unroll 8
        for (int u = 0; u < CH; ++u) {
            // x_t from padded LDS (uniform address -> broadcast)
            const float4 xv4 = *(const float4*)(xc + u * PSTRIDE);
            const float x4v  = *(const float*)(xc + u * PSTRIDE + 16);
            float2 x01; x01.x = xv4.x; x01.y = xv4.y;
            float2 x23; x23.x = xv4.z; x23.y = xv4.w;

            // x-dot (off the recurrence chain): 2 pk_mul + 1 fma
            float t0 = fmaf(x4v, wi4, bias);
            float2 p01, p23;
            pk_mul(p01, x01, wi01);
            pk_mul(p23, x23, wi23);

            // h broadcasts: readlane -> SGPR pairs (uniform)
            float2 h01, h23, h45, h67, h89;
            h01.x = readlane_f(hval, 0);  h01.y = readlane_f(hval, 4);
            h23.x = readlane_f(hval, 8);  h23.y = readlane_f(hval, 12);
            h45.x = readlane_f(hval, 16); h45.y = readlane_f(hval, 20);
            h67.x = readlane_f(hval, 24); h67.y = readlane_f(hval, 28);
            h89.x = readlane_f(hval, 32); h89.y = readlane_f(hval, 36);

            // h-dot: 5 pk_fma (scalar-pair src0, weight-pair src1)
            pk_fma_s(p01, h01, w01);
            pk_fma_s(p23, h23, w23);
            pk_fma_s(p01, h45, w45);
            pk_fma_s(p23, h67, w67);
            pk_fma_s(p01, h89, w89);

            // reduce: 1 pk_add + 2 scalar adds
            pk_add(p01, p01, p23);
            const float acc = (p01.x + p01.y) + t0;

            // branchless sigmoid / KC*tanh
            const float e = __builtin_amdgcn_exp2f(acc);
            const float s = __builtin_amdgcn_rcpf(1.f + e);
            const float act = fmaf(s, am, ac);

            // quad gather: pure-VALU DPP broadcasts
            const float iv = quad_bcast<0>(act);
            const float fv = quad_bcast<1>(act);
            const float gs = quad_bcast<2>(act);   // already KC*g
            const float ov = quad_bcast<3>(act);

            // cs = KC*c:  cs' = f*cs + i*(KC*g);  tanh(c) = 2*rcp(1+exp2(cs))-1
            cs = fmaf(fv, cs, iv * gs);
            const float e2 = __builtin_amdgcn_exp2f(cs);
            const float th = fmaf(__builtin_amdgcn_rcpf(1.f + e2), 2.f, -1.f);
            hval = ov * th;

            // batched store: lane (j,k) captures step ==k (mod 4);
            // 40 lanes store a contiguous 160B segment every 4th step.
            keep = ((u & 3) == k) ? hval : keep;     // cndmask, masks hoisted
            if ((u & 3) == 3) {
                const int off = ((u & 7) == 3) ? 0 : 40;   // imm 0 / 160B
                if (active) outp[off] = keep;
            }
            if ((u & 7) == 7) outp += 80;            // +320B per unroll-8
        }

        // park the prefetched chunk into the other LDS buffer (padded scatter)
        if (c + 1 < NCHUNK) {
            char* dst = xs[(c + 1) & 1];
#pragma unroll
            for (int q = 0; q < II; q++) {
                *(float*)(dst + wa[q][0]) = pf[q].x;
                *(float*)(dst + wa[q][1]) = pf[q].y;
                *(float*)(dst + wa[q][2]) = pf[q].z;
                *(float*)(dst + wa[q][3]) = pf[q].w;
            }
        }
    }
}

extern "C" void kernel_launch(void* const* d_in, const int* in_sizes, int n_in,
                              void* d_out, int out_size, void* d_ws, size_t ws_size,
                              hipStream_t stream) {
    const float* x    = (const float*)d_in[0];
    const float* h0   = (const float*)d_in[1];
    const float* c0   = (const float*)d_in[2];
    const float* W_ih = (const float*)d_in[3];
    const float* W_hh = (const float*)d_in[4];
    const float* b_ih = (const float*)d_in[5];
    const float* b_hh = (const float*)d_in[6];
    float* out = (float*)d_out;

    lstm_wave_kernel<<<dim3(BB), dim3(64), 0, stream>>>(
        x, h0, c0, W_ih, W_hh, b_ih, b_hh, out);
}